// Round 7
// baseline (241.075 us; speedup 1.0000x reference)
//
#include <hip/hip_runtime.h>

// GCN: 2x (GCNConv + ReLU) + FC.  N=100000, E=1600000, F: 128 -> 64 -> 64 -> 32. fp32.
//
// R15: mm2/fc fused into agg kernels (row-local). aggmm block owns 64 nodes;
// relu -> 64x64 bf16 LDS tile -> K=64 MFMA vs LDS W^T -> next table.
// R16-R18: aggmm gather restructures; 49 -> 43.7us then plateau.
// R19/R19b: partition restructure (binA range-reservation staging, rescale
// folded into mm1, zeroK not memset). 241.9 -> 228.9us.
// R20: scanT removed (sortB self-prefix) BUT binA EPB 4096->2048 doubled the
// fixed-cost LDS scans: +2.9us net.  => R21 reverts binA to EPB=4096, keeps
// self-prefix sortB.
// R21: aggmm <=32-edge fast path (P(deg<=32)=.9998): cooperative-load idxA
// and idxB, issue up to EIGHT 4-edge gather groups back-to-back (2x in-flight
// loads), then accumulate; full groups unmasked (srt pre-masked by sortB),
// only the final partial group (<4 edges) pays clamp+mask.  deg>32 drains
// 16-edge chunks first (rare).  Targets the two separated ~500cy latency
// windows per node that R18-R20 counters kept showing (stall = 54%).

#define THREADS 256
#define THREADS_A 512
#define BIN_T 512
#define EPB 4096
#define BKT 256
#define CAP 8064
#define SORT_CAP 8192

typedef unsigned short ushort_t;
typedef __attribute__((ext_vector_type(8))) short short8;
typedef __attribute__((ext_vector_type(4))) float f32x4;
typedef __attribute__((ext_vector_type(2))) float f32x2;

__device__ __forceinline__ ushort_t f2bf(float f) {  // round-to-nearest-even
    unsigned u = __float_as_uint(f);
    u += 0x7FFFu + ((u >> 16) & 1u);
    return (ushort_t)(u >> 16);
}
__device__ __forceinline__ float bflo(unsigned v) { return __uint_as_float(v << 16); }
__device__ __forceinline__ float bfhi(unsigned v) { return __uint_as_float(v & 0xFFFF0000u); }

// ---- Kernel 0: zero the bucket counters (graph-capture-safe memset) --------

__global__ __launch_bounds__(BIN_T) void zeroK_kernel(int* __restrict__ p, int n) {
    const int i = (int)threadIdx.x;
    if (i < n) p[i] = 0;
}

// ---- Kernel 1: binA - bucket count + range reservation + coalesced scatter -
// (R19b version: EPB=4096, u32 eaddr; 62KB LDS, 2 blocks/CU - the per-block
// fixed-cost scan makes fewer/bigger blocks the better trade, per R20.)

__global__ __launch_bounds__(BIN_T) void binA_kernel(const int* __restrict__ src,
                                                     const int* __restrict__ dst, int E,
                                                     int nb,
                                                     int* __restrict__ cntg,
                                                     unsigned* __restrict__ stagePad) {
    __shared__ unsigned ebuf[EPB];    // packed (d&255)<<17 | src, load order
    __shared__ unsigned ebuf2[EPB];   // bucket-sorted entries
    __shared__ unsigned eaddr[EPB];   // global address per sorted slot
    __shared__ ushort_t ebkt[EPB];    // bucket id per loaded entry
    __shared__ int cnt[BIN_T], cur[BIN_T], gb[BIN_T];
    const int t = threadIdx.x;
    const int e0 = blockIdx.x * EPB;
    const int n = min(EPB, E - e0);
    cnt[t] = 0;
    __syncthreads();
    for (int i = t; i < n; i += BIN_T) {
        const int d = dst[e0 + i];
        const int s = src[e0 + i];
        ebuf[i] = ((unsigned)(d & (BKT - 1)) << 17) | (unsigned)s;
        const int b = d >> 8;
        ebkt[i] = (ushort_t)b;
        atomicAdd(&cnt[b], 1);
    }
    __syncthreads();
    // Inclusive scan of cnt in cur -> exclusive local offsets.
    const int v = cnt[t];
    cur[t] = v;
    __syncthreads();
    for (int off = 1; off < BIN_T; off <<= 1) {
        int u = (t >= off) ? cur[t - off] : 0;
        __syncthreads();
        cur[t] += u;
        __syncthreads();
    }
    const int excl = cur[t] - v;
    if (t < nb && v > 0) {
        const int resv = atomicAdd(&cntg[t], v);
        gb[t] = t * CAP + resv - excl;
    }
    __syncthreads();
    cur[t] = excl;
    __syncthreads();
    // Reorder into bucket-sorted LDS + compute final global addresses.
    for (int i = t; i < n; i += BIN_T) {
        const int b = (int)ebkt[i];
        const int p = atomicAdd(&cur[b], 1);
        ebuf2[p] = ebuf[i];
        eaddr[p] = (unsigned)(gb[b] + p);
    }
    __syncthreads();
    // Coalesced-run output (eaddr increments by 1 within each bucket run).
    for (int i = t; i < n; i += BIN_T)
        stagePad[eaddr[i]] = ebuf2[i];
}

// ---- Kernel 2: per-bucket counting sort + row/dinv (self-computed prefix) --

__global__ __launch_bounds__(THREADS) void sortB_kernel(const unsigned* __restrict__ stagePad,
                                                        const int* __restrict__ cntg,
                                                        int nb, int N,
                                                        int* __restrict__ row,
                                                        float* __restrict__ dinv,
                                                        unsigned* __restrict__ srt) {
    __shared__ unsigned buf[SORT_CAP];
    __shared__ int cnt[BKT], cur[BKT], scn[BKT];
    __shared__ int red[THREADS];
    const int b = blockIdx.x, t = threadIdx.x;
    // Bucket prefix: bs = sum(cntg[0..b-1]) via strided loads + tree reduce.
    int part = 0;
    for (int j = t; j < b; j += THREADS) part += cntg[j];
    red[t] = part;
    __syncthreads();
#pragma unroll
    for (int off = THREADS / 2; off > 0; off >>= 1) {
        if (t < off) red[t] += red[t + off];
        __syncthreads();
    }
    const int bs = red[0];
    const int m = cntg[b];
    const unsigned* base = stagePad + (size_t)b * CAP;
    cnt[t] = 0;
    __syncthreads();
    for (int i = t; i < m; i += THREADS) {
        const unsigned v = base[i];
        buf[i] = v;
        atomicAdd(&cnt[v >> 17], 1);
    }
    __syncthreads();
    const int c = cnt[t];
    scn[t] = c;
    __syncthreads();
    for (int off = 1; off < BKT; off <<= 1) {
        int u = (t >= off) ? scn[t - off] : 0;
        __syncthreads();
        scn[t] += u;
        __syncthreads();
    }
    const int excl = scn[t] - c;
    cur[t] = excl;
    const int node = b * BKT + t;
    if (node < N) {
        row[node] = bs + excl;
        dinv[node] = rsqrtf((float)c + 1.0f);
    }
    __syncthreads();
    for (int i = t; i < m; i += THREADS) {
        const unsigned v = buf[i];
        const int pos = atomicAdd(&cur[v >> 17], 1);
        srt[bs + pos] = v & 0x1FFFFu;
    }
}

// ---- Kernel 3: MFMA mm1 (fp32 in, dinv-scaled bf16 out) --------------------

template <int K, int M>
__global__ __launch_bounds__(THREADS) void mm1_kernel(const float* __restrict__ Xf,
                                                      const float* __restrict__ W,
                                                      const float* __restrict__ dinv,
                                                      ushort_t* __restrict__ Yv, int N) {
    constexpr int XROW = K + 4;
    constexpr int XB = 64 * XROW * 4;
    constexpr int WROW = K + 8;
    constexpr int WB = M * WROW * 2;
    constexpr int CB = 64 * M * 4;
    constexpr int SMEM = (XB + WB > CB) ? (XB + WB) : CB;
    __shared__ __align__(16) char smem[SMEM];
    const int t = threadIdx.x;
    const int row0 = (int)blockIdx.x * 64;

    ushort_t* WsU = (ushort_t*)(smem + XB);
    for (int i = t; i < K * M; i += THREADS) {
        const int k = i / M, m = i % M;
        WsU[m * WROW + k] = f2bf(W[i]);
    }
    float* XsF = (float*)smem;
    for (int i = t; i < 64 * K / 4; i += THREADS) {
        const int r = i / (K / 4), kc = i % (K / 4);
        const unsigned gr = (unsigned)min(row0 + r, N - 1);
        *(float4*)(XsF + r * XROW + kc * 4) = *(const float4*)(Xf + (size_t)gr * K + kc * 4);
    }
    __syncthreads();

    const int w = t >> 6, lane = t & 63;
    const int m0 = w * 16, lm = lane & 15, q = lane >> 4;
    f32x4 acc[M / 16];
#pragma unroll
    for (int c = 0; c < M / 16; ++c) acc[c] = (f32x4)0.0f;

#pragma unroll
    for (int s = 0; s < K / 32; ++s) {
        const float* xr = (const float*)smem + (size_t)(m0 + lm) * XROW + s * 32 + q * 8;
        const float4 f0 = *(const float4*)xr;
        const float4 f1 = *(const float4*)(xr + 4);
        short8 a;
        a[0] = (short)f2bf(f0.x); a[1] = (short)f2bf(f0.y);
        a[2] = (short)f2bf(f0.z); a[3] = (short)f2bf(f0.w);
        a[4] = (short)f2bf(f1.x); a[5] = (short)f2bf(f1.y);
        a[6] = (short)f2bf(f1.z); a[7] = (short)f2bf(f1.w);
#pragma unroll
        for (int c = 0; c < M / 16; ++c) {
            const short8 b = *(const short8*)(WsU + (size_t)(c * 16 + lm) * WROW + s * 32 + q * 8);
            acc[c] = __builtin_amdgcn_mfma_f32_16x16x32_bf16(a, b, acc[c], 0, 0, 0);
        }
    }
    __syncthreads();
    float* Cs = (float*)smem;
#pragma unroll
    for (int c = 0; c < M / 16; ++c)
#pragma unroll
        for (int r = 0; r < 4; ++r)
            Cs[(size_t)(m0 + q * 4 + r) * M + c * 16 + lm] = acc[c][r];
    __syncthreads();

    for (int g = t; g < 64 * M / 4; g += THREADS) {
        const int r = g / (M / 4);
        const int gr = row0 + r;
        if (gr >= N) continue;
        float4 o = *(const float4*)(Cs + (size_t)g * 4);
        const float dv = dinv[gr];
        o.x *= dv; o.y *= dv; o.z *= dv; o.w *= dv;
        const int col = (g % (M / 4)) * 4;
        ushort4 pk = {f2bf(o.x), f2bf(o.y), f2bf(o.z), f2bf(o.w)};
        *(ushort4*)(Yv + (size_t)gr * M + col) = pk;
    }
}

// ---- Fused aggregate + row-local MFMA matmul -------------------------------
// Block owns 64 nodes; 8 waves, wave w handles nodes w*8..w*8+7 sequentially.
// Phase 1 (gather): 16 lanes/edge (dwordx2).  Fast path (deg<=32): both idx
// vectors cooperative-loaded, up to 8 gather groups issued back-to-back, THEN
// accumulated; full groups unmasked.  deg>32 drains 16-edge chunks first.
// Phase 2 (MFMA):  Y[64][M] = Rl @ W; wave = (row-strip w>>1, col-half w&1).
// MODE 1: Y *= dinv -> bf16 pair table.  MODE 2: Y += fbias -> fp32 out.

template <int M, int MODE>
__global__ __launch_bounds__(THREADS_A) void aggmm_kernel(const unsigned* __restrict__ srt,
                                                          const int* __restrict__ row,
                                                          const float* __restrict__ dinv,
                                                          const unsigned* __restrict__ H2,
                                                          const float* __restrict__ abias,
                                                          const float* __restrict__ W,
                                                          const float* __restrict__ fbias,
                                                          void* __restrict__ Yv,
                                                          int N, int E) {
    constexpr int K = 64;
    constexpr int RROW = 36;                 // relu-tile row stride in dwords (72 ushorts)
    constexpr int RB = 64 * RROW * 4;        // 9216 B
    constexpr int WROW = K + 8;              // 72 ushorts
    constexpr int WB = M * WROW * 2;
    constexpr int CB = 64 * M * 4;
    constexpr int SMEM = (RB + WB > CB) ? (RB + WB) : CB;
    __shared__ __align__(16) char smem[SMEM];
    const int t = threadIdx.x;
    const int w = t >> 6, lane = t & 63;
    const int row0 = blockIdx.x * 64;

    // Stage W^T bf16 (phase 1 doesn't read it; barrier below covers it).
    ushort_t* WsU = (ushort_t*)(smem + RB);
    for (int i = t; i < K * M; i += THREADS_A) {
        const int k = i / M, m = i % M;
        WsU[m * WROW + k] = f2bf(W[i]);
    }

    // Phase 1: gather+relu for this wave's 8 nodes.
    unsigned* Rl = (unsigned*)smem;
    const int col2 = lane & 15;              // dword-pair within 32-dword row
    const int slot = lane >> 4;              // edge slot 0..3
    const unsigned roff = (unsigned)(col2 * 2);
    const unsigned cap = (unsigned)(N - 1);
    const int node00 = row0 + w * 8;
    // Wave-invariant bias (hoisted off the per-node chain).
    const float4 bias4 = *(const float4*)(abias + col2 * 4);
    // Row/dinv prefetch: lanes 0..9 hold row[node00+lane] (E past the end).
    int rv;
    float dvv;
    {
        const int ridx = node00 + (int)lane;
        const bool okr = ridx < N;
        rv = okr ? row[ridx] : E;
        dvv = okr ? dinv[ridx] : 0.0f;
    }
    // Prefetch node-0 chunk-0 idx (16 lanes cooperative, broadcast pattern).
    int sc = __shfl(rv, 0, 64);
    int ec = __shfl(rv, 1, 64);
    unsigned idx0 = srt[sc + col2];
#pragma unroll 1
    for (int i = 0; i < 8; ++i) {
        const int node = node00 + i;
        if (node >= N) break;
        const int start = sc, end = ec;
        unsigned idxA = idx0;
        if (i < 7) {  // prefetch next node's first idx during this node
            sc = __shfl(rv, i + 1, 64);
            ec = __shfl(rv, i + 2, 64);
            idx0 = srt[sc + col2];
        }
        // Self-loop row, issued early (independent of gathers).
        const uint2 sv = *(const uint2*)(H2 + (((unsigned)node << 5) + roff));
        f32x2 a0 = {0.0f, 0.0f}, a1 = {0.0f, 0.0f};
        int base = start;
        // Slow prefix (deg > 32 only): drain 16-edge chunks.
        while (end - base > 32) {
            const unsigned idxN = srt[base + 16 + col2];
#pragma unroll
            for (int g = 0; g < 4; ++g) {
                const unsigned r = (unsigned)__shfl((int)idxA, g * 4 + slot, 64);
                const uint2 v = *(const uint2*)(H2 + ((r << 5) + roff));
                a0 += (f32x2){bflo(v.x), bfhi(v.x)};
                a1 += (f32x2){bflo(v.y), bfhi(v.y)};
            }
            base += 16;
            idxA = idxN;
        }
        // Fast path: rem in [0,32].  idxA covers edges 0..15, idxB 16..31.
        const int rem = end - base;
        unsigned idxB = 0;
        if (rem > 16) idxB = srt[base + 16 + col2];
        const int fullg = rem >> 2;          // full 4-edge groups (0..8)
        const int part = rem & 3;
        // Full groups: all loads issue back-to-back (8 in flight), unmasked
        // (srt entries are pre-masked to 0x1FFFF by sortB).
#pragma unroll
        for (int g = 0; g < 8; ++g) {
            if (g >= fullg) break;           // wave-uniform
            const unsigned iv = (g < 4) ? idxA : idxB;
            const unsigned r = (unsigned)__shfl((int)iv, (g & 3) * 4 + slot, 64);
            const uint2 v = *(const uint2*)(H2 + ((r << 5) + roff));
            a0 += (f32x2){bflo(v.x), bfhi(v.x)};
            a1 += (f32x2){bflo(v.y), bfhi(v.y)};
        }
        if (part) {                          // final partial group (<4 edges)
            const int g = fullg;             // 0..7 when part>0
            const unsigned iv = (g < 4) ? idxA : idxB;
            unsigned r = (unsigned)__shfl((int)iv, (g & 3) * 4 + slot, 64) & 0x1FFFFu;
            r = min(r, cap);                 // garbage past end
            uint2 v = *(const uint2*)(H2 + ((r << 5) + roff));
            const bool ok = slot < part;
            v.x = ok ? v.x : 0u;
            v.y = ok ? v.y : 0u;
            a0 += (f32x2){bflo(v.x), bfhi(v.x)};
            a1 += (f32x2){bflo(v.y), bfhi(v.y)};
        }
        // Reduce across the 4 edge slots (lanes 16 apart share col2).
        a0.x += __shfl_xor(a0.x, 16, 64);
        a0.y += __shfl_xor(a0.y, 16, 64);
        a1.x += __shfl_xor(a1.x, 16, 64);
        a1.y += __shfl_xor(a1.y, 16, 64);
        a0.x += __shfl_xor(a0.x, 32, 64);
        a0.y += __shfl_xor(a0.y, 32, 64);
        a1.x += __shfl_xor(a1.x, 32, 64);
        a1.y += __shfl_xor(a1.y, 32, 64);
        const float d = __shfl(dvv, i, 64);
        if (slot == 0) {
            const float o0 = fmaxf(fmaf(a0.x + bflo(sv.x), d, bias4.x), 0.0f);
            const float o1 = fmaxf(fmaf(a0.y + bfhi(sv.x), d, bias4.y), 0.0f);
            const float o2 = fmaxf(fmaf(a1.x + bflo(sv.y), d, bias4.z), 0.0f);
            const float o3 = fmaxf(fmaf(a1.y + bfhi(sv.y), d, bias4.w), 0.0f);
            uint2 pk;
            pk.x = ((unsigned)f2bf(o1) << 16) | (unsigned)f2bf(o0);
            pk.y = ((unsigned)f2bf(o3) << 16) | (unsigned)f2bf(o2);
            *(uint2*)(Rl + (size_t)(w * 8 + i) * RROW + col2 * 2) = pk;
        }
    }
    __syncthreads();

    // Phase 2: MFMA over the relu tile. Wave = (row-strip, col-half).
    constexpr int TW = M / 32;               // col tiles per wave (64->2, 32->1)
    const int m0 = (w >> 1) * 16, lm = lane & 15, q = lane >> 4;
    const int c0 = (w & 1) * TW;
    f32x4 acc[TW];
#pragma unroll
    for (int c = 0; c < TW; ++c) acc[c] = (f32x4)0.0f;
#pragma unroll
    for (int s = 0; s < K / 32; ++s) {
        const short8 a = *(const short8*)((const ushort_t*)Rl + (size_t)(m0 + lm) * 72 + s * 32 + q * 8);
#pragma unroll
        for (int c = 0; c < TW; ++c) {
            const short8 b = *(const short8*)(WsU + (size_t)((c0 + c) * 16 + lm) * WROW + s * 32 + q * 8);
            acc[c] = __builtin_amdgcn_mfma_f32_16x16x32_bf16(a, b, acc[c], 0, 0, 0);
        }
    }
    __syncthreads();   // Rl/Ws dead; reuse as C [64][M] f32
    float* Cs = (float*)smem;
#pragma unroll
    for (int c = 0; c < TW; ++c)
#pragma unroll
        for (int r = 0; r < 4; ++r)
            Cs[(size_t)(m0 + q * 4 + r) * M + (c0 + c) * 16 + lm] = acc[c][r];
    __syncthreads();

    for (int g = t; g < 64 * M / 4; g += THREADS_A) {
        const int r = g / (M / 4);
        const int gr = row0 + r;
        if (gr >= N) continue;
        float4 o = *(const float4*)(Cs + (size_t)g * 4);
        const int col = (g % (M / 4)) * 4;
        if (MODE == 1) {
            const float d = dinv[gr];
            o.x *= d; o.y *= d; o.z *= d; o.w *= d;
            ushort4 pk = {f2bf(o.x), f2bf(o.y), f2bf(o.z), f2bf(o.w)};
            *(ushort4*)((ushort_t*)Yv + (size_t)gr * M + col) = pk;
        } else {
            o.x += fbias[col]; o.y += fbias[col + 1];
            o.z += fbias[col + 2]; o.w += fbias[col + 3];
            *(float4*)((float*)Yv + (size_t)gr * M + col) = o;
        }
    }
}

// ---- Launch ----------------------------------------------------------------

extern "C" void kernel_launch(void* const* d_in, const int* in_sizes, int n_in,
                              void* d_out, int out_size, void* d_ws, size_t ws_size,
                              hipStream_t stream) {
    const float* x   = (const float*)d_in[0];
    const int*   ei  = (const int*)d_in[1];   // [2, E] int32
    const float* W1  = (const float*)d_in[3];
    const float* b1  = (const float*)d_in[4];
    const float* W2  = (const float*)d_in[5];
    const float* b2  = (const float*)d_in[6];
    const float* Wfc = (const float*)d_in[7];
    const float* bfc = (const float*)d_in[8];
    float* out = (float*)d_out;

    const int N = in_sizes[0] / 128;
    const int E = in_sizes[1] / 2;
    const int* src = ei;
    const int* dst = ei + E;

    const int nb   = (N + BKT - 1) / BKT;     // 391 buckets
    const int nblk = (E + EPB - 1) / EPB;     // 391 edge-chunks

    // Workspace (256 B-aligned slices).
    char* p = (char*)d_ws;
    auto alloc = [&](size_t bytes) { char* r = p; p += (bytes + 255) & ~(size_t)255; return r; };
    int*      cntg   = (int*)alloc((size_t)nb * 4);
    unsigned* srt    = (unsigned*)alloc((size_t)E * 4);
    int*      row    = (int*)alloc((size_t)N * 4);     // also absorbs agg tail over-reads
    float*    dinv   = (float*)alloc((size_t)N * 4);
    ushort_t* bufH   = (ushort_t*)alloc((size_t)N * 64 * 2);   // H1 table (bf16, *dinv)
    ushort_t* bufR   = (ushort_t*)alloc((size_t)N * 64 * 2);   // H2 table; doubles as stagePad
    unsigned* stagePad = (unsigned*)bufR;     // nb*CAP*4 = 12.61 MB <= 12.8 MB, dead before aggmm-1

    const int mmB = (N + 63) / 64;

    // 0) zero bucket counters (kernel, not hipMemsetAsync: graph-capture-safe).
    zeroK_kernel<<<1, BIN_T, 0, stream>>>(cntg, nb);
    // 1) bucket-bin edges with atomic range reservation + coalesced scatter.
    binA_kernel<<<nblk, BIN_T, 0, stream>>>(src, dst, E, nb, cntg, stagePad);
    // 2) per-bucket counting sort (self-computed bucket prefix) -> srt, row, dinv.
    sortB_kernel<<<nb, THREADS, 0, stream>>>(stagePad, cntg, nb, N, row, dinv, srt);
    // 3) mm1 MFMA, dinv folded into epilogue.
    mm1_kernel<128, 64><<<mmB, THREADS, 0, stream>>>(x, W1, dinv, bufH, N);
    // 4) agg layer1 + mm2 fused -> H2 table (bf16, *dinv).
    aggmm_kernel<64, 1><<<mmB, THREADS_A, 0, stream>>>(
        srt, row, dinv, (const unsigned*)bufH, b1, W2, nullptr, bufR, N, E);
    // 5) agg layer2 + fc fused -> fp32 out (+bfc).
    aggmm_kernel<32, 2><<<mmB, THREADS_A, 0, stream>>>(
        srt, row, dinv, (const unsigned*)bufR, b2, Wfc, bfc, out, N, E);
}

// Round 8
// 226.772 us; speedup vs baseline: 1.0631x; 1.0631x over previous
//
#include <hip/hip_runtime.h>

// GCN: 2x (GCNConv + ReLU) + FC.  N=100000, E=1600000, F: 128 -> 64 -> 64 -> 32. fp32.
//
// R15: mm2/fc fused into agg kernels (row-local). aggmm block owns 64 nodes;
// relu -> 64x64 bf16 LDS tile -> K=64 MFMA vs LDS W^T -> next table.
// R16-R18: aggmm gather restructures; 49 -> 42.7us (R18 = best measured).
// R19/R19b: partition restructure (binA range-reservation staging, rescale
// folded into mm1, zeroK not memset). 241.9 -> 228.9us.
// R20: EPB 4096->2048 regressed (+2.9us): binA's per-block scan is the fixed
// cost; fewer/bigger blocks win.  Self-prefix sortB (scanT removed) is good.
// R21: aggmm "8 groups back-to-back" fast path REGRESSED (42.8 -> 50.2us):
// unroll+break+select defeated compiler load batching (VALUBusy 46->39%,
// VGPR 32->28 = serialized).  R18's minimal-control-flow loop is the local
// optimum; its 42.7us is L2/L3-miss latency on random 128B rows (FETCH
// 83.8MB >> 12.8MB table), not instruction-schedule-bound.
// R22: bank the measured-best combo: R18 aggmm verbatim + R19b binA (EPB
// 4096) + R20 self-prefix sortB.  No new mechanisms.

#define THREADS 256
#define THREADS_A 512
#define BIN_T 512
#define EPB 4096
#define BKT 256
#define CAP 8064
#define SORT_CAP 8192

typedef unsigned short ushort_t;
typedef __attribute__((ext_vector_type(8))) short short8;
typedef __attribute__((ext_vector_type(4))) float f32x4;
typedef __attribute__((ext_vector_type(2))) float f32x2;

__device__ __forceinline__ ushort_t f2bf(float f) {  // round-to-nearest-even
    unsigned u = __float_as_uint(f);
    u += 0x7FFFu + ((u >> 16) & 1u);
    return (ushort_t)(u >> 16);
}
__device__ __forceinline__ float bflo(unsigned v) { return __uint_as_float(v << 16); }
__device__ __forceinline__ float bfhi(unsigned v) { return __uint_as_float(v & 0xFFFF0000u); }

// ---- Kernel 0: zero the bucket counters (graph-capture-safe memset) --------

__global__ __launch_bounds__(BIN_T) void zeroK_kernel(int* __restrict__ p, int n) {
    const int i = (int)threadIdx.x;
    if (i < n) p[i] = 0;
}

// ---- Kernel 1: binA - bucket count + range reservation + coalesced scatter -

__global__ __launch_bounds__(BIN_T) void binA_kernel(const int* __restrict__ src,
                                                     const int* __restrict__ dst, int E,
                                                     int nb,
                                                     int* __restrict__ cntg,
                                                     unsigned* __restrict__ stagePad) {
    __shared__ unsigned ebuf[EPB];    // packed (d&255)<<17 | src, load order
    __shared__ unsigned ebuf2[EPB];   // bucket-sorted entries
    __shared__ unsigned eaddr[EPB];   // global address per sorted slot
    __shared__ ushort_t ebkt[EPB];    // bucket id per loaded entry
    __shared__ int cnt[BIN_T], cur[BIN_T], gb[BIN_T];
    const int t = threadIdx.x;
    const int e0 = blockIdx.x * EPB;
    const int n = min(EPB, E - e0);
    cnt[t] = 0;
    __syncthreads();
    for (int i = t; i < n; i += BIN_T) {
        const int d = dst[e0 + i];
        const int s = src[e0 + i];
        ebuf[i] = ((unsigned)(d & (BKT - 1)) << 17) | (unsigned)s;
        const int b = d >> 8;
        ebkt[i] = (ushort_t)b;
        atomicAdd(&cnt[b], 1);
    }
    __syncthreads();
    // Inclusive scan of cnt in cur -> exclusive local offsets.
    const int v = cnt[t];
    cur[t] = v;
    __syncthreads();
    for (int off = 1; off < BIN_T; off <<= 1) {
        int u = (t >= off) ? cur[t - off] : 0;
        __syncthreads();
        cur[t] += u;
        __syncthreads();
    }
    const int excl = cur[t] - v;
    if (t < nb && v > 0) {
        const int resv = atomicAdd(&cntg[t], v);
        gb[t] = t * CAP + resv - excl;
    }
    __syncthreads();
    cur[t] = excl;
    __syncthreads();
    // Reorder into bucket-sorted LDS + compute final global addresses.
    for (int i = t; i < n; i += BIN_T) {
        const int b = (int)ebkt[i];
        const int p = atomicAdd(&cur[b], 1);
        ebuf2[p] = ebuf[i];
        eaddr[p] = (unsigned)(gb[b] + p);
    }
    __syncthreads();
    // Coalesced-run output (eaddr increments by 1 within each bucket run).
    for (int i = t; i < n; i += BIN_T)
        stagePad[eaddr[i]] = ebuf2[i];
}

// ---- Kernel 2: per-bucket counting sort + row/dinv (self-computed prefix) --

__global__ __launch_bounds__(THREADS) void sortB_kernel(const unsigned* __restrict__ stagePad,
                                                        const int* __restrict__ cntg,
                                                        int nb, int N,
                                                        int* __restrict__ row,
                                                        float* __restrict__ dinv,
                                                        unsigned* __restrict__ srt) {
    __shared__ unsigned buf[SORT_CAP];
    __shared__ int cnt[BKT], cur[BKT], scn[BKT];
    __shared__ int red[THREADS];
    const int b = blockIdx.x, t = threadIdx.x;
    // Bucket prefix: bs = sum(cntg[0..b-1]) via strided loads + tree reduce.
    int part = 0;
    for (int j = t; j < b; j += THREADS) part += cntg[j];
    red[t] = part;
    __syncthreads();
#pragma unroll
    for (int off = THREADS / 2; off > 0; off >>= 1) {
        if (t < off) red[t] += red[t + off];
        __syncthreads();
    }
    const int bs = red[0];
    const int m = cntg[b];
    const unsigned* base = stagePad + (size_t)b * CAP;
    cnt[t] = 0;
    __syncthreads();
    for (int i = t; i < m; i += THREADS) {
        const unsigned v = base[i];
        buf[i] = v;
        atomicAdd(&cnt[v >> 17], 1);
    }
    __syncthreads();
    const int c = cnt[t];
    scn[t] = c;
    __syncthreads();
    for (int off = 1; off < BKT; off <<= 1) {
        int u = (t >= off) ? scn[t - off] : 0;
        __syncthreads();
        scn[t] += u;
        __syncthreads();
    }
    const int excl = scn[t] - c;
    cur[t] = excl;
    const int node = b * BKT + t;
    if (node < N) {
        row[node] = bs + excl;
        dinv[node] = rsqrtf((float)c + 1.0f);
    }
    __syncthreads();
    for (int i = t; i < m; i += THREADS) {
        const unsigned v = buf[i];
        const int pos = atomicAdd(&cur[v >> 17], 1);
        srt[bs + pos] = v & 0x1FFFFu;
    }
}

// ---- Kernel 3: MFMA mm1 (fp32 in, dinv-scaled bf16 out) --------------------

template <int K, int M>
__global__ __launch_bounds__(THREADS) void mm1_kernel(const float* __restrict__ Xf,
                                                      const float* __restrict__ W,
                                                      const float* __restrict__ dinv,
                                                      ushort_t* __restrict__ Yv, int N) {
    constexpr int XROW = K + 4;
    constexpr int XB = 64 * XROW * 4;
    constexpr int WROW = K + 8;
    constexpr int WB = M * WROW * 2;
    constexpr int CB = 64 * M * 4;
    constexpr int SMEM = (XB + WB > CB) ? (XB + WB) : CB;
    __shared__ __align__(16) char smem[SMEM];
    const int t = threadIdx.x;
    const int row0 = (int)blockIdx.x * 64;

    ushort_t* WsU = (ushort_t*)(smem + XB);
    for (int i = t; i < K * M; i += THREADS) {
        const int k = i / M, m = i % M;
        WsU[m * WROW + k] = f2bf(W[i]);
    }
    float* XsF = (float*)smem;
    for (int i = t; i < 64 * K / 4; i += THREADS) {
        const int r = i / (K / 4), kc = i % (K / 4);
        const unsigned gr = (unsigned)min(row0 + r, N - 1);
        *(float4*)(XsF + r * XROW + kc * 4) = *(const float4*)(Xf + (size_t)gr * K + kc * 4);
    }
    __syncthreads();

    const int w = t >> 6, lane = t & 63;
    const int m0 = w * 16, lm = lane & 15, q = lane >> 4;
    f32x4 acc[M / 16];
#pragma unroll
    for (int c = 0; c < M / 16; ++c) acc[c] = (f32x4)0.0f;

#pragma unroll
    for (int s = 0; s < K / 32; ++s) {
        const float* xr = (const float*)smem + (size_t)(m0 + lm) * XROW + s * 32 + q * 8;
        const float4 f0 = *(const float4*)xr;
        const float4 f1 = *(const float4*)(xr + 4);
        short8 a;
        a[0] = (short)f2bf(f0.x); a[1] = (short)f2bf(f0.y);
        a[2] = (short)f2bf(f0.z); a[3] = (short)f2bf(f0.w);
        a[4] = (short)f2bf(f1.x); a[5] = (short)f2bf(f1.y);
        a[6] = (short)f2bf(f1.z); a[7] = (short)f2bf(f1.w);
#pragma unroll
        for (int c = 0; c < M / 16; ++c) {
            const short8 b = *(const short8*)(WsU + (size_t)(c * 16 + lm) * WROW + s * 32 + q * 8);
            acc[c] = __builtin_amdgcn_mfma_f32_16x16x32_bf16(a, b, acc[c], 0, 0, 0);
        }
    }
    __syncthreads();
    float* Cs = (float*)smem;
#pragma unroll
    for (int c = 0; c < M / 16; ++c)
#pragma unroll
        for (int r = 0; r < 4; ++r)
            Cs[(size_t)(m0 + q * 4 + r) * M + c * 16 + lm] = acc[c][r];
    __syncthreads();

    for (int g = t; g < 64 * M / 4; g += THREADS) {
        const int r = g / (M / 4);
        const int gr = row0 + r;
        if (gr >= N) continue;
        float4 o = *(const float4*)(Cs + (size_t)g * 4);
        const float dv = dinv[gr];
        o.x *= dv; o.y *= dv; o.z *= dv; o.w *= dv;
        const int col = (g % (M / 4)) * 4;
        ushort4 pk = {f2bf(o.x), f2bf(o.y), f2bf(o.z), f2bf(o.w)};
        *(ushort4*)(Yv + (size_t)gr * M + col) = pk;
    }
}

// ---- Fused aggregate + row-local MFMA matmul (R18 version, best measured) --
// Block owns 64 nodes; 8 waves, wave w handles nodes w*8..w*8+7 sequentially.
// Phase 1 (gather): 16 lanes/edge (dwordx2), 4 edges per wave-instr; chunk
// idx vectors prefetched one node ahead.  relu(dinv*(Hself+sum)+abias) ->
// bf16 LDS tile Rl[64][72u].
// Phase 2 (MFMA):  Y[64][M] = Rl @ W; wave = (row-strip w>>1, col-half w&1).
// MODE 1: Y *= dinv -> bf16 pair table.  MODE 2: Y += fbias -> fp32 out.

template <int M, int MODE>
__global__ __launch_bounds__(THREADS_A) void aggmm_kernel(const unsigned* __restrict__ srt,
                                                          const int* __restrict__ row,
                                                          const float* __restrict__ dinv,
                                                          const unsigned* __restrict__ H2,
                                                          const float* __restrict__ abias,
                                                          const float* __restrict__ W,
                                                          const float* __restrict__ fbias,
                                                          void* __restrict__ Yv,
                                                          int N, int E) {
    constexpr int K = 64;
    constexpr int RROW = 36;                 // relu-tile row stride in dwords (72 ushorts)
    constexpr int RB = 64 * RROW * 4;        // 9216 B
    constexpr int WROW = K + 8;              // 72 ushorts
    constexpr int WB = M * WROW * 2;
    constexpr int CB = 64 * M * 4;
    constexpr int SMEM = (RB + WB > CB) ? (RB + WB) : CB;
    __shared__ __align__(16) char smem[SMEM];
    const int t = threadIdx.x;
    const int w = t >> 6, lane = t & 63;
    const int row0 = blockIdx.x * 64;

    // Stage W^T bf16 (phase 1 doesn't read it; barrier below covers it).
    ushort_t* WsU = (ushort_t*)(smem + RB);
    for (int i = t; i < K * M; i += THREADS_A) {
        const int k = i / M, m = i % M;
        WsU[m * WROW + k] = f2bf(W[i]);
    }

    // Phase 1: gather+relu for this wave's 8 nodes.
    unsigned* Rl = (unsigned*)smem;
    const int col2 = lane & 15;              // dword-pair within 32-dword row
    const int slot = lane >> 4;              // edge slot 0..3
    const unsigned roff = (unsigned)(col2 * 2);
    const unsigned cap = (unsigned)(N - 1);
    const int node00 = row0 + w * 8;
    // Wave-invariant bias (hoisted off the per-node chain).
    const float4 bias4 = *(const float4*)(abias + col2 * 4);
    // Row/dinv prefetch: lanes 0..9 hold row[node00+lane] (E past the end).
    int rv;
    float dvv;
    {
        const int ridx = node00 + (int)lane;
        const bool okr = ridx < N;
        rv = okr ? row[ridx] : E;
        dvv = okr ? dinv[ridx] : 0.0f;
    }
    // Prefetch node-0 chunk-0 idx (16 lanes cooperative, broadcast pattern).
    int sc = __shfl(rv, 0, 64);
    int ec = __shfl(rv, 1, 64);
    unsigned idx0 = srt[sc + col2];
#pragma unroll 1
    for (int i = 0; i < 8; ++i) {
        const int node = node00 + i;
        if (node >= N) break;
        const int start = sc, end = ec;
        unsigned idx = idx0;
        if (i < 7) {  // prefetch next node's chunk-0 idx during this node
            sc = __shfl(rv, i + 1, 64);
            ec = __shfl(rv, i + 2, 64);
            idx0 = srt[sc + col2];
        }
        // Self-loop row, issued early (independent of gathers).
        const uint2 sv = *(const uint2*)(H2 + (((unsigned)node << 5) + roff));
        f32x2 a0 = {0.0f, 0.0f}, a1 = {0.0f, 0.0f};
        int base = start;
        while (base + 16 <= end) {
            unsigned idxn = 0;
            if (base + 16 < end)  // prefetch next chunk idx before the adds
                idxn = srt[base + 16 + col2];
#pragma unroll
            for (int g = 0; g < 4; ++g) {
                const unsigned r = (unsigned)__shfl((int)idx, g * 4 + slot, 64);
                const uint2 v = *(const uint2*)(H2 + ((r << 5) + roff));
                a0 += (f32x2){bflo(v.x), bfhi(v.x)};
                a1 += (f32x2){bflo(v.y), bfhi(v.y)};
            }
            base += 16;
            idx = idxn;
        }
        const int rem = end - base;
        if (rem > 0) {
#pragma unroll
            for (int g = 0; g < 4; ++g) {
                if (g * 4 >= rem) break;               // wave-uniform
                const int e = g * 4 + slot;
                unsigned r = (unsigned)__shfl((int)idx, e, 64) & 0x1FFFFu;
                r = min(r, cap);                       // garbage past end
                uint2 v = *(const uint2*)(H2 + ((r << 5) + roff));
                const bool ok = e < rem;
                v.x = ok ? v.x : 0u;
                v.y = ok ? v.y : 0u;
                a0 += (f32x2){bflo(v.x), bfhi(v.x)};
                a1 += (f32x2){bflo(v.y), bfhi(v.y)};
            }
        }
        // Reduce across the 4 edge slots (lanes 16 apart share col2).
        a0.x += __shfl_xor(a0.x, 16, 64);
        a0.y += __shfl_xor(a0.y, 16, 64);
        a1.x += __shfl_xor(a1.x, 16, 64);
        a1.y += __shfl_xor(a1.y, 16, 64);
        a0.x += __shfl_xor(a0.x, 32, 64);
        a0.y += __shfl_xor(a0.y, 32, 64);
        a1.x += __shfl_xor(a1.x, 32, 64);
        a1.y += __shfl_xor(a1.y, 32, 64);
        const float d = __shfl(dvv, i, 64);
        if (slot == 0) {
            const float o0 = fmaxf(fmaf(a0.x + bflo(sv.x), d, bias4.x), 0.0f);
            const float o1 = fmaxf(fmaf(a0.y + bfhi(sv.x), d, bias4.y), 0.0f);
            const float o2 = fmaxf(fmaf(a1.x + bflo(sv.y), d, bias4.z), 0.0f);
            const float o3 = fmaxf(fmaf(a1.y + bfhi(sv.y), d, bias4.w), 0.0f);
            uint2 pk;
            pk.x = ((unsigned)f2bf(o1) << 16) | (unsigned)f2bf(o0);
            pk.y = ((unsigned)f2bf(o3) << 16) | (unsigned)f2bf(o2);
            *(uint2*)(Rl + (size_t)(w * 8 + i) * RROW + col2 * 2) = pk;
        }
    }
    __syncthreads();

    // Phase 2: MFMA over the relu tile. Wave = (row-strip, col-half).
    constexpr int TW = M / 32;               // col tiles per wave (64->2, 32->1)
    const int m0 = (w >> 1) * 16, lm = lane & 15, q = lane >> 4;
    const int c0 = (w & 1) * TW;
    f32x4 acc[TW];
#pragma unroll
    for (int c = 0; c < TW; ++c) acc[c] = (f32x4)0.0f;
#pragma unroll
    for (int s = 0; s < K / 32; ++s) {
        const short8 a = *(const short8*)((const ushort_t*)Rl + (size_t)(m0 + lm) * 72 + s * 32 + q * 8);
#pragma unroll
        for (int c = 0; c < TW; ++c) {
            const short8 b = *(const short8*)(WsU + (size_t)((c0 + c) * 16 + lm) * WROW + s * 32 + q * 8);
            acc[c] = __builtin_amdgcn_mfma_f32_16x16x32_bf16(a, b, acc[c], 0, 0, 0);
        }
    }
    __syncthreads();   // Rl/Ws dead; reuse as C [64][M] f32
    float* Cs = (float*)smem;
#pragma unroll
    for (int c = 0; c < TW; ++c)
#pragma unroll
        for (int r = 0; r < 4; ++r)
            Cs[(size_t)(m0 + q * 4 + r) * M + (c0 + c) * 16 + lm] = acc[c][r];
    __syncthreads();

    for (int g = t; g < 64 * M / 4; g += THREADS_A) {
        const int r = g / (M / 4);
        const int gr = row0 + r;
        if (gr >= N) continue;
        float4 o = *(const float4*)(Cs + (size_t)g * 4);
        const int col = (g % (M / 4)) * 4;
        if (MODE == 1) {
            const float d = dinv[gr];
            o.x *= d; o.y *= d; o.z *= d; o.w *= d;
            ushort4 pk = {f2bf(o.x), f2bf(o.y), f2bf(o.z), f2bf(o.w)};
            *(ushort4*)((ushort_t*)Yv + (size_t)gr * M + col) = pk;
        } else {
            o.x += fbias[col]; o.y += fbias[col + 1];
            o.z += fbias[col + 2]; o.w += fbias[col + 3];
            *(float4*)((float*)Yv + (size_t)gr * M + col) = o;
        }
    }
}

// ---- Launch ----------------------------------------------------------------

extern "C" void kernel_launch(void* const* d_in, const int* in_sizes, int n_in,
                              void* d_out, int out_size, void* d_ws, size_t ws_size,
                              hipStream_t stream) {
    const float* x   = (const float*)d_in[0];
    const int*   ei  = (const int*)d_in[1];   // [2, E] int32
    const float* W1  = (const float*)d_in[3];
    const float* b1  = (const float*)d_in[4];
    const float* W2  = (const float*)d_in[5];
    const float* b2  = (const float*)d_in[6];
    const float* Wfc = (const float*)d_in[7];
    const float* bfc = (const float*)d_in[8];
    float* out = (float*)d_out;

    const int N = in_sizes[0] / 128;
    const int E = in_sizes[1] / 2;
    const int* src = ei;
    const int* dst = ei + E;

    const int nb   = (N + BKT - 1) / BKT;     // 391 buckets
    const int nblk = (E + EPB - 1) / EPB;     // 391 edge-chunks

    // Workspace (256 B-aligned slices).
    char* p = (char*)d_ws;
    auto alloc = [&](size_t bytes) { char* r = p; p += (bytes + 255) & ~(size_t)255; return r; };
    int*      cntg   = (int*)alloc((size_t)nb * 4);
    unsigned* srt    = (unsigned*)alloc((size_t)E * 4);
    int*      row    = (int*)alloc((size_t)N * 4);     // also absorbs agg tail over-reads
    float*    dinv   = (float*)alloc((size_t)N * 4);
    ushort_t* bufH   = (ushort_t*)alloc((size_t)N * 64 * 2);   // H1 table (bf16, *dinv)
    ushort_t* bufR   = (ushort_t*)alloc((size_t)N * 64 * 2);   // H2 table; doubles as stagePad
    unsigned* stagePad = (unsigned*)bufR;     // nb*CAP*4 = 12.61 MB <= 12.8 MB, dead before aggmm-1

    const int mmB = (N + 63) / 64;

    // 0) zero bucket counters (kernel, not hipMemsetAsync: graph-capture-safe).
    zeroK_kernel<<<1, BIN_T, 0, stream>>>(cntg, nb);
    // 1) bucket-bin edges with atomic range reservation + coalesced scatter.
    binA_kernel<<<nblk, BIN_T, 0, stream>>>(src, dst, E, nb, cntg, stagePad);
    // 2) per-bucket counting sort (self-computed bucket prefix) -> srt, row, dinv.
    sortB_kernel<<<nb, THREADS, 0, stream>>>(stagePad, cntg, nb, N, row, dinv, srt);
    // 3) mm1 MFMA, dinv folded into epilogue.
    mm1_kernel<128, 64><<<mmB, THREADS, 0, stream>>>(x, W1, dinv, bufH, N);
    // 4) agg layer1 + mm2 fused -> H2 table (bf16, *dinv).
    aggmm_kernel<64, 1><<<mmB, THREADS_A, 0, stream>>>(
        srt, row, dinv, (const unsigned*)bufH, b1, W2, nullptr, bufR, N, E);
    // 5) agg layer2 + fc fused -> fp32 out (+bfc).
    aggmm_kernel<32, 2><<<mmB, THREADS_A, 0, stream>>>(
        srt, row, dinv, (const unsigned*)bufR, b2, Wfc, bfc, out, N, E);
}